// Round 18
// baseline (116.043 us; speedup 1.0000x reference)
//
#include <hip/hip_runtime.h>
#include <hip/hip_bf16.h>

typedef __attribute__((ext_vector_type(8))) short bf16x8;
typedef __attribute__((ext_vector_type(4))) float f32x4;
typedef __attribute__((ext_vector_type(16))) float f32x16;
typedef __attribute__((ext_vector_type(4))) unsigned short u16x4;
typedef __attribute__((ext_vector_type(8))) unsigned short u16x8v;

#define S_LEN 2048
#define NHEAD 16
#define HDIM 64
#define DIM 1024

__device__ __forceinline__ unsigned short f2bf(float f) {
    union { float f; unsigned u; } x; x.f = f;
    unsigned r = x.u + 0x7FFFu + ((x.u >> 16) & 1u);
    return (unsigned short)(r >> 16);
}
__device__ __forceinline__ unsigned short f2bf_fast(float f) {
    union { float f; unsigned u; } x; x.f = f;
    return (unsigned short)((x.u + 0x8000u) >> 16);
}

__device__ __forceinline__ f32x4 mfma16(bf16x8 a, bf16x8 b, f32x4 c) {
    return __builtin_amdgcn_mfma_f32_16x16x32_bf16(a, b, c, 0, 0, 0);
}
__device__ __forceinline__ f32x16 mfma32(bf16x8 a, bf16x8 b, f32x16 c) {
    return __builtin_amdgcn_mfma_f32_32x32x16_bf16(a, b, c, 0, 0, 0);
}

__device__ __forceinline__ float fexp2(float x) {
#if __has_builtin(__builtin_amdgcn_exp2f)
    return __builtin_amdgcn_exp2f(x);
#else
    return exp2f(x);
#endif
}

__device__ __forceinline__ void gl_lds16(const void* g, void* l) {
    __builtin_amdgcn_global_load_lds(
        (const __attribute__((address_space(1))) unsigned int*)g,
        (__attribute__((address_space(3))) unsigned int*)l, 16, 0, 0);
}

// ---------- fused prep: xconv (blocks 0..2047) + wtrans qkv + wtrans proj ----------
__device__ __forceinline__ void wtrans_body(const float* __restrict__ W,
                                            unsigned short* __restrict__ Wt,
                                            int K, int N, int k0, int n0,
                                            float (*lds)[65], int tid) {
    for (int idx = tid; idx < 1024; idx += 256) {
        int row = idx >> 4, c = (idx & 15) << 2;
        float4 v = *reinterpret_cast<const float4*>(&W[(size_t)(k0 + row) * N + n0 + c]);
        lds[row][c] = v.x; lds[row][c + 1] = v.y; lds[row][c + 2] = v.z; lds[row][c + 3] = v.w;
    }
    __syncthreads();
    for (int idx = tid; idx < 1024; idx += 256) {
        int row = idx >> 4, c = (idx & 15) << 2;
        u16x4 o;
        o[0] = f2bf(lds[c][row]);     o[1] = f2bf(lds[c + 1][row]);
        o[2] = f2bf(lds[c + 2][row]); o[3] = f2bf(lds[c + 3][row]);
        *reinterpret_cast<u16x4*>(&Wt[(size_t)(n0 + row) * K + k0 + c]) = o;
    }
}

__global__ __launch_bounds__(256) void prep_kernel(const float* __restrict__ X,
                                                   unsigned short* __restrict__ Xb,
                                                   const float* __restrict__ Wq,
                                                   unsigned short* __restrict__ Wqt,
                                                   const float* __restrict__ Wp,
                                                   unsigned short* __restrict__ Wpt) {
    __shared__ float lds[64][65];
    const int b = blockIdx.x, tid = threadIdx.x;
    if (b < 2048) {
        size_t i = ((size_t)b * 256 + tid) * 8;
        float4 a = *reinterpret_cast<const float4*>(&X[i]);
        float4 c = *reinterpret_cast<const float4*>(&X[i + 4]);
        u16x8v o;
        o[0] = f2bf(a.x); o[1] = f2bf(a.y); o[2] = f2bf(a.z); o[3] = f2bf(a.w);
        o[4] = f2bf(c.x); o[5] = f2bf(c.y); o[6] = f2bf(c.z); o[7] = f2bf(c.w);
        *reinterpret_cast<u16x8v*>(&Xb[i]) = o;
    } else if (b < 2816) {
        int idx = b - 2048;
        wtrans_body(Wq, Wqt, 1024, 3072, (idx & 15) * 64, (idx >> 4) * 64, lds, tid);
    } else {
        int idx = b - 2816;
        wtrans_body(Wp, Wpt, 1024, 1024, (idx & 15) * 64, (idx >> 4) * 64, lds, tid);
    }
}

// ---------- GEMM: 128x128 tile, BK=64, 8 waves x (64x32), single-buffer (r15) ----------
template <int MODE>
__global__ __launch_bounds__(512) void gemm_kernel(
    const unsigned short* __restrict__ Ab, const unsigned short* __restrict__ Bt,
    const float* __restrict__ bias,
    unsigned short* __restrict__ Qb, unsigned short* __restrict__ Kb,
    unsigned short* __restrict__ Vt, float* __restrict__ outf) {
    __shared__ unsigned short Alds[128 * 64];   // 16KB, 128B rows, swizzled
    __shared__ unsigned short Blds[128 * 64];
    const int tid = threadIdx.x;
    const int m0 = blockIdx.x * 128, n0 = blockIdx.y * 128;
    const int wid = tid >> 6, lane = tid & 63;
    const int wm = wid >> 2, wn = wid & 3;      // 2 x 4 wave grid
    const int lr = lane & 15, lg = lane >> 4;

    const char* Abase = (const char*)(Ab + (size_t)m0 * 1024);
    const char* Bbase = (const char*)(Bt + (size_t)n0 * 1024);

    int srcOff[2], dstOff[2];
#pragma unroll
    for (int i = 0; i < 2; ++i) {
        int off = i * 8192 + tid * 16;
        int row = off >> 7, col = off & 127;
        srcOff[i] = row * 2048 + (col ^ ((row & 7) << 4));
        dstOff[i] = off;
    }
    const int swz = (lr & 7) << 4;

    f32x4 acc[4][2] = {};

    for (int kt = 0; kt < 16; ++kt) {
        __syncthreads();
#pragma unroll
        for (int i = 0; i < 2; ++i) {
            gl_lds16(Abase + srcOff[i] + kt * 128, (char*)Alds + dstOff[i]);
            gl_lds16(Bbase + srcOff[i] + kt * 128, (char*)Blds + dstOff[i]);
        }
        __syncthreads();

#pragma unroll
        for (int ks = 0; ks < 2; ++ks) {
            bf16x8 af[4], bfr[2];
#pragma unroll
            for (int i = 0; i < 4; ++i)
                af[i] = *reinterpret_cast<const bf16x8*>(
                    (const char*)Alds + (wm * 64 + i * 16 + lr) * 128 + ((ks * 64 + lg * 16) ^ swz));
#pragma unroll
            for (int j = 0; j < 2; ++j)
                bfr[j] = *reinterpret_cast<const bf16x8*>(
                    (const char*)Blds + (wn * 32 + j * 16 + lr) * 128 + ((ks * 64 + lg * 16) ^ swz));
            __builtin_amdgcn_s_setprio(1);
#pragma unroll
            for (int i = 0; i < 4; ++i)
#pragma unroll
                for (int j = 0; j < 2; ++j)
                    acc[i][j] = mfma16(af[i], bfr[j], acc[i][j]);
            __builtin_amdgcn_s_setprio(0);
        }
    }

    if constexpr (MODE == 0) {
        const int sec = n0 >> 10;
#pragma unroll
        for (int j = 0; j < 2; ++j) {
            int gn = n0 + wn * 32 + j * 16 + lr;
            float bv = bias[gn];
            int nn = gn & 1023, h = nn >> 6, d = nn & 63;
            if (sec == 2) {
#pragma unroll
                for (int i = 0; i < 4; ++i) {
                    int sb = m0 + wm * 64 + i * 16 + lg * 4;
                    size_t bhv = (size_t)((sb >> 11) * NHEAD + h);
                    u16x4 pv;
#pragma unroll
                    for (int r = 0; r < 4; ++r) pv[r] = f2bf(acc[i][j][r] + bv);
                    *reinterpret_cast<u16x4*>(&Vt[(bhv * HDIM + d) * S_LEN + (sb & 2047)]) = pv;
                }
            } else {
#pragma unroll
                for (int i = 0; i < 4; ++i) {
#pragma unroll
                    for (int r = 0; r < 4; ++r) {
                        int m = m0 + wm * 64 + i * 16 + lg * 4 + r;
                        int b_ = m >> 11, s_ = m & 2047;
                        size_t bh = (size_t)(b_ * NHEAD + h);
                        float v = acc[i][j][r] + bv;
                        if (sec == 0)
                            Qb[(bh * S_LEN + s_) * HDIM + d] = f2bf(v * 0.18033688f);  // 1/8*log2(e)
                        else
                            Kb[(bh * S_LEN + s_) * HDIM + d] = f2bf(v);
                    }
                }
            }
        }
    } else {
#pragma unroll
        for (int j = 0; j < 2; ++j) {
            int gn = n0 + wn * 32 + j * 16 + lr;
            float bv = bias[gn];
#pragma unroll
            for (int i = 0; i < 4; ++i) {
#pragma unroll
                for (int r = 0; r < 4; ++r) {
                    int m = m0 + wm * 64 + i * 16 + lg * 4 + r;
                    outf[(size_t)m * DIM + gn] = acc[i][j][r] + bv;
                }
            }
        }
    }
}

// ---------- flash attention: 16 waves (4q x 4k split), natural VGPR (~60) ----------
// r15 structure with the launch bound FIXED: no min-waves arg -> no forced
// VGPR cap -> no spill. 60 VGPR <= 64 lets HW run 8 waves/SIMD (32/CU).
__device__ __forceinline__ void repack32(const f32x16& p, bf16x8 (&pa)[2]) {
#pragma unroll
    for (int k2 = 0; k2 < 2; ++k2) {
        const int rb = 8 * k2;
        unsigned aw[2], bw[2];
#pragma unroll
        for (int u = 0; u < 2; ++u) {
            unsigned a, b;
            asm("v_cvt_pk_bf16_f32 %0, %1, %2"
                : "=v"(a) : "v"(p[rb + 2 * u]), "v"(p[rb + 2 * u + 1]));
            asm("v_cvt_pk_bf16_f32 %0, %1, %2"
                : "=v"(b) : "v"(p[rb + 4 + 2 * u]), "v"(p[rb + 4 + 2 * u + 1]));
            asm volatile("v_permlane32_swap_b32 %0, %1" : "+v"(a), "+v"(b));
            aw[u] = a; bw[u] = b;
        }
        union { unsigned w[4]; bf16x8 v; } pu;
        pu.w[0] = aw[0]; pu.w[1] = aw[1]; pu.w[2] = bw[0]; pu.w[3] = bw[1];
        pa[k2] = pu.v;
    }
}

#define NPAIR 16   // 16 pairs x 128 keys = 2048
__global__ __launch_bounds__(1024) void attn_kernel(const unsigned short* __restrict__ Qb,
                                                    const unsigned short* __restrict__ Kb,
                                                    const unsigned short* __restrict__ Vt,
                                                    unsigned short* __restrict__ Ob) {
    __shared__ char smem[65536 + 2048];           // 2 bufs x 32KB + cls scratch
    const int L = blockIdx.x;                     // 0..511
    const int xcd = L & 7, slot = L >> 3;
    const int bh = xcd + 8 * (slot & 3);          // 4 heads per XCD -> K/V L2-resident
    const int qblk = slot >> 2;                   // 0..15
    const int wid = threadIdx.x >> 6;             // 0..15
    const int lane = threadIdx.x & 63;
    const int l31 = lane & 31, hi = lane >> 5;
    const int qs = wid & 3, khq = wid >> 2;       // khq 0..3
    const int t2 = khq >> 1, khs = khq & 1;
    const int q0 = qblk * 128 + qs * 32;

    const unsigned short* qrow = &Qb[((size_t)bh * S_LEN + q0 + l31) * HDIM];
    bf16x8 qf[4];
#pragma unroll
    for (int kst = 0; kst < 4; ++kst)
        qf[kst] = *reinterpret_cast<const bf16x8*>(&qrow[kst * 16 + hi * 8]);

    bf16x8 onesf;
#pragma unroll
    for (int j = 0; j < 8; ++j) onesf[j] = (short)0x3F80;   // bf16 1.0

    const char* kT = (const char*)&Kb[(size_t)bh * S_LEN * HDIM];  // tile t at +t*8192
    const char* vT = (const char*)&Vt[(size_t)bh * HDIM * S_LEN];  // tile t at +t*128

    // staging: 32 chunks per pair (ids 0-15 K, 16-31 V); wave stages ids 2*wid, 2*wid+1
    const char* sbase = (wid < 8) ? kT : vT;
    const int pairStride = (wid < 8) ? 16384 : 256;
    int srcOff[2], dstOff[2];
#pragma unroll
    for (int i = 0; i < 2; ++i) {
        int id = 2 * wid + i;
        if (id < 16) {
            int st2 = (id >> 3) & 1, skhs = (id >> 2) & 1, kst = id & 3;
            srcOff[i] = st2 * 8192 + (skhs * 32 + l31) * 128 + kst * 32 + hi * 16;
        } else {
            int c = id - 16;
            int st2 = (c >> 3) & 1, skhs = (c >> 2) & 1, dt = (c >> 1) & 1, k2 = c & 1;
            srcOff[i] = st2 * 128 + (dt * 32 + l31) * 4096 + skhs * 64 + k2 * 32 + hi * 16;
        }
        dstOff[i] = id * 1024;
    }

    f32x16 acc[2] = {};
    f32x16 sacc = {};                              // MFMA row-sums (P . ones)

    // prologue: stage pair 0 -> buf 0
#pragma unroll
    for (int i = 0; i < 2; ++i)
        gl_lds16(sbase + srcOff[i], smem + dstOff[i]);
    __syncthreads();

    const int cofs = (t2 * 8 + khs * 4) * 1024;
    int cur = 0;
    for (int pt = 0; pt < NPAIR; ++pt) {
        if (pt + 1 < NPAIR) {
#pragma unroll
            for (int i = 0; i < 2; ++i)
                gl_lds16(sbase + (pt + 1) * pairStride + srcOff[i],
                         smem + (cur ^ 1) * 32768 + dstOff[i]);
        }
        const char* kbb = smem + cur * 32768 + cofs + lane * 16;
        const char* vbb = smem + cur * 32768 + 16384 + cofs + lane * 16;

        // QK^T swapped: lane holds q=l31, local key = (r&3)+4*hi+8*(r>>2)
        f32x16 p = {};
        __builtin_amdgcn_s_setprio(1);
#pragma unroll
        for (int kst = 0; kst < 4; ++kst) {
            bf16x8 kb = *reinterpret_cast<const bf16x8*>(kbb + kst * 1024);
            p = mfma32(kb, qf[kst], p);
        }
        __builtin_amdgcn_s_setprio(0);

#pragma unroll
        for (int r = 0; r < 16; ++r) p[r] = fexp2(p[r]);
        bf16x8 pa[2];
        repack32(p, pa);

        __builtin_amdgcn_s_setprio(1);
        sacc = mfma32(pa[0], onesf, sacc);         // row-sums on the MFMA pipe
        sacc = mfma32(pa[1], onesf, sacc);
#pragma unroll
        for (int dt = 0; dt < 2; ++dt)
#pragma unroll
            for (int k2 = 0; k2 < 2; ++k2) {
                bf16x8 vb = *reinterpret_cast<const bf16x8*>(vbb + (dt * 2 + k2) * 1024);
                acc[dt] = mfma32(pa[k2], vb, acc[dt]);
            }
        __builtin_amdgcn_s_setprio(0);

        __syncthreads();   // staging complete for next pair + buf reuse safe
        cur ^= 1;
    }

    // ---- 2-stage cross-wave combine over khq (0 <- 1, 2 <- 3, then 0 <- 2) ----
    float* caccA = (float*)smem;                  // 32KB: [qs][dt][r][lane]
    float* caccB = (float*)(smem + 32768);        // 32KB
    float* clsA  = (float*)(smem + 65536);        // [qs][q] 512B
    float* clsB  = (float*)(smem + 65536 + 1024);

    if (khq == 1 || khq == 3) {
        float* dst = (khq == 1) ? caccA : caccB;
        float* dcl = (khq == 1) ? clsA : clsB;
#pragma unroll
        for (int dt = 0; dt < 2; ++dt)
#pragma unroll
            for (int r = 0; r < 16; ++r)
                dst[qs * 2048 + dt * 1024 + r * 64 + lane] = acc[dt][r];
        if (l31 == 0) {
#pragma unroll
            for (int r = 0; r < 16; ++r) {
                int rq = (r & 3) + 8 * (r >> 2) + 4 * hi;
                dcl[qs * 32 + rq] = sacc[r];
            }
        }
    }
    __syncthreads();
    if (khq == 0 || khq == 2) {
        const float* src = (khq == 0) ? caccA : caccB;
        const float* scl = (khq == 0) ? clsA : clsB;
#pragma unroll
        for (int dt = 0; dt < 2; ++dt)
#pragma unroll
            for (int r = 0; r < 16; ++r)
                acc[dt][r] += src[qs * 2048 + dt * 1024 + r * 64 + lane];
#pragma unroll
        for (int r = 0; r < 16; ++r) {
            int rq = (r & 3) + 8 * (r >> 2) + 4 * hi;
            sacc[r] += scl[qs * 32 + rq];
        }
    }
    __syncthreads();
    if (khq == 2) {
#pragma unroll
        for (int dt = 0; dt < 2; ++dt)
#pragma unroll
            for (int r = 0; r < 16; ++r)
                caccA[qs * 2048 + dt * 1024 + r * 64 + lane] = acc[dt][r];
        if (l31 == 0) {
#pragma unroll
            for (int r = 0; r < 16; ++r) {
                int rq = (r & 3) + 8 * (r >> 2) + 4 * hi;
                clsA[qs * 32 + rq] = sacc[r];
            }
        }
    }
    __syncthreads();
    if (khq == 0) {
#pragma unroll
        for (int dt = 0; dt < 2; ++dt)
#pragma unroll
            for (int r = 0; r < 16; ++r)
                acc[dt][r] += caccA[qs * 2048 + dt * 1024 + r * 64 + lane];

        const int b_ = bh >> 4, h = bh & 15;
        float inv[16];
#pragma unroll
        for (int r = 0; r < 16; ++r) {
            int rq = (r & 3) + 8 * (r >> 2) + 4 * hi;
            inv[r] = 1.f / (sacc[r] + clsA[qs * 32 + rq]);
        }
#pragma unroll
        for (int dt = 0; dt < 2; ++dt)
#pragma unroll
            for (int r = 0; r < 16; ++r) {
                int rq = (r & 3) + 8 * (r >> 2) + 4 * hi;
                int q = q0 + rq;
                Ob[((size_t)(b_ * S_LEN + q)) * DIM + h * HDIM + dt * 32 + l31] =
                    f2bf_fast(acc[dt][r] * inv[r]);
            }
    }
}

extern "C" void kernel_launch(void* const* d_in, const int* in_sizes, int n_in,
                              void* d_out, int out_size, void* d_ws, size_t ws_size,
                              hipStream_t stream) {
    const float* x      = (const float*)d_in[0];
    const float* qkv_w  = (const float*)d_in[1];
    const float* qkv_b  = (const float*)d_in[2];
    const float* proj_w = (const float*)d_in[3];
    const float* proj_b = (const float*)d_in[4];
    float* out = (float*)d_out;

    unsigned short* Wqkvt = (unsigned short*)d_ws;         // [3072][1024] bf16
    unsigned short* Wpt   = Wqkvt + 3072 * 1024;           // [1024][1024] bf16
    unsigned short* Qb    = Wpt + 1024 * 1024;             // [32][2048][64] bf16 (scale*log2e folded)
    unsigned short* Kb    = Qb + 32 * 2048 * 64;           // [32][2048][64]
    unsigned short* Vt    = Kb + 32 * 2048 * 64;           // [32][64][2048]
    unsigned short* Ob    = Vt + 32 * 2048 * 64;           // [4096][1024] bf16
    unsigned short* Xb    = Ob + 4096 * 1024;              // [4096][1024] bf16

    prep_kernel<<<3072, 256, 0, stream>>>(x, Xb, qkv_w, Wqkvt, proj_w, Wpt);

    gemm_kernel<0><<<dim3(32, 24), 512, 0, stream>>>(Xb, Wqkvt, qkv_b, Qb, Kb, Vt, nullptr);
    attn_kernel<<<512, 1024, 0, stream>>>(Qb, Kb, Vt, Ob);
    gemm_kernel<1><<<dim3(32, 8), 512, 0, stream>>>(Ob, Wpt, proj_b, nullptr, nullptr, nullptr, out);
}

// Round 19
// 108.364 us; speedup vs baseline: 1.0709x; 1.0709x over previous
//
#include <hip/hip_runtime.h>
#include <hip/hip_bf16.h>

typedef __attribute__((ext_vector_type(8))) short bf16x8;
typedef __attribute__((ext_vector_type(4))) float f32x4;
typedef __attribute__((ext_vector_type(16))) float f32x16;
typedef __attribute__((ext_vector_type(4))) unsigned short u16x4;
typedef __attribute__((ext_vector_type(8))) unsigned short u16x8v;

#define S_LEN 2048
#define NHEAD 16
#define HDIM 64
#define DIM 1024

__device__ __forceinline__ unsigned short f2bf(float f) {
    union { float f; unsigned u; } x; x.f = f;
    unsigned r = x.u + 0x7FFFu + ((x.u >> 16) & 1u);
    return (unsigned short)(r >> 16);
}
__device__ __forceinline__ unsigned short f2bf_fast(float f) {
    union { float f; unsigned u; } x; x.f = f;
    return (unsigned short)((x.u + 0x8000u) >> 16);
}

__device__ __forceinline__ f32x4 mfma16(bf16x8 a, bf16x8 b, f32x4 c) {
    return __builtin_amdgcn_mfma_f32_16x16x32_bf16(a, b, c, 0, 0, 0);
}
__device__ __forceinline__ f32x16 mfma32(bf16x8 a, bf16x8 b, f32x16 c) {
    return __builtin_amdgcn_mfma_f32_32x32x16_bf16(a, b, c, 0, 0, 0);
}

__device__ __forceinline__ float fexp2(float x) {
#if __has_builtin(__builtin_amdgcn_exp2f)
    return __builtin_amdgcn_exp2f(x);
#else
    return exp2f(x);
#endif
}

__device__ __forceinline__ void gl_lds16(const void* g, void* l) {
    __builtin_amdgcn_global_load_lds(
        (const __attribute__((address_space(1))) unsigned int*)g,
        (__attribute__((address_space(3))) unsigned int*)l, 16, 0, 0);
}

// ---------- fused prep: xconv (blocks 0..2047) + wtrans qkv + wtrans proj ----------
__device__ __forceinline__ void wtrans_body(const float* __restrict__ W,
                                            unsigned short* __restrict__ Wt,
                                            int K, int N, int k0, int n0,
                                            float (*lds)[65], int tid) {
    for (int idx = tid; idx < 1024; idx += 256) {
        int row = idx >> 4, c = (idx & 15) << 2;
        float4 v = *reinterpret_cast<const float4*>(&W[(size_t)(k0 + row) * N + n0 + c]);
        lds[row][c] = v.x; lds[row][c + 1] = v.y; lds[row][c + 2] = v.z; lds[row][c + 3] = v.w;
    }
    __syncthreads();
    for (int idx = tid; idx < 1024; idx += 256) {
        int row = idx >> 4, c = (idx & 15) << 2;
        u16x4 o;
        o[0] = f2bf(lds[c][row]);     o[1] = f2bf(lds[c + 1][row]);
        o[2] = f2bf(lds[c + 2][row]); o[3] = f2bf(lds[c + 3][row]);
        *reinterpret_cast<u16x4*>(&Wt[(size_t)(n0 + row) * K + k0 + c]) = o;
    }
}

__global__ __launch_bounds__(256) void prep_kernel(const float* __restrict__ X,
                                                   unsigned short* __restrict__ Xb,
                                                   const float* __restrict__ Wq,
                                                   unsigned short* __restrict__ Wqt,
                                                   const float* __restrict__ Wp,
                                                   unsigned short* __restrict__ Wpt) {
    __shared__ float lds[64][65];
    const int b = blockIdx.x, tid = threadIdx.x;
    if (b < 2048) {
        size_t i = ((size_t)b * 256 + tid) * 8;
        float4 a = *reinterpret_cast<const float4*>(&X[i]);
        float4 c = *reinterpret_cast<const float4*>(&X[i + 4]);
        u16x8v o;
        o[0] = f2bf(a.x); o[1] = f2bf(a.y); o[2] = f2bf(a.z); o[3] = f2bf(a.w);
        o[4] = f2bf(c.x); o[5] = f2bf(c.y); o[6] = f2bf(c.z); o[7] = f2bf(c.w);
        *reinterpret_cast<u16x8v*>(&Xb[i]) = o;
    } else if (b < 2816) {
        int idx = b - 2048;
        wtrans_body(Wq, Wqt, 1024, 3072, (idx & 15) * 64, (idx >> 4) * 64, lds, tid);
    } else {
        int idx = b - 2816;
        wtrans_body(Wp, Wpt, 1024, 1024, (idx & 15) * 64, (idx >> 4) * 64, lds, tid);
    }
}

// ---------- GEMM: 128x128 tile, BK=64, 8 waves x (64x32), single-buffer (r15) ----------
template <int MODE>
__global__ __launch_bounds__(512) void gemm_kernel(
    const unsigned short* __restrict__ Ab, const unsigned short* __restrict__ Bt,
    const float* __restrict__ bias,
    unsigned short* __restrict__ Qb, unsigned short* __restrict__ Kb,
    unsigned short* __restrict__ Vt, float* __restrict__ outf) {
    __shared__ unsigned short Alds[128 * 64];   // 16KB, 128B rows, swizzled
    __shared__ unsigned short Blds[128 * 64];
    const int tid = threadIdx.x;
    const int m0 = blockIdx.x * 128, n0 = blockIdx.y * 128;
    const int wid = tid >> 6, lane = tid & 63;
    const int wm = wid >> 2, wn = wid & 3;      // 2 x 4 wave grid
    const int lr = lane & 15, lg = lane >> 4;

    const char* Abase = (const char*)(Ab + (size_t)m0 * 1024);
    const char* Bbase = (const char*)(Bt + (size_t)n0 * 1024);

    int srcOff[2], dstOff[2];
#pragma unroll
    for (int i = 0; i < 2; ++i) {
        int off = i * 8192 + tid * 16;
        int row = off >> 7, col = off & 127;
        srcOff[i] = row * 2048 + (col ^ ((row & 7) << 4));
        dstOff[i] = off;
    }
    const int swz = (lr & 7) << 4;

    f32x4 acc[4][2] = {};

    for (int kt = 0; kt < 16; ++kt) {
        __syncthreads();
#pragma unroll
        for (int i = 0; i < 2; ++i) {
            gl_lds16(Abase + srcOff[i] + kt * 128, (char*)Alds + dstOff[i]);
            gl_lds16(Bbase + srcOff[i] + kt * 128, (char*)Blds + dstOff[i]);
        }
        __syncthreads();

#pragma unroll
        for (int ks = 0; ks < 2; ++ks) {
            bf16x8 af[4], bfr[2];
#pragma unroll
            for (int i = 0; i < 4; ++i)
                af[i] = *reinterpret_cast<const bf16x8*>(
                    (const char*)Alds + (wm * 64 + i * 16 + lr) * 128 + ((ks * 64 + lg * 16) ^ swz));
#pragma unroll
            for (int j = 0; j < 2; ++j)
                bfr[j] = *reinterpret_cast<const bf16x8*>(
                    (const char*)Blds + (wn * 32 + j * 16 + lr) * 128 + ((ks * 64 + lg * 16) ^ swz));
            __builtin_amdgcn_s_setprio(1);
#pragma unroll
            for (int i = 0; i < 4; ++i)
#pragma unroll
                for (int j = 0; j < 2; ++j)
                    acc[i][j] = mfma16(af[i], bfr[j], acc[i][j]);
            __builtin_amdgcn_s_setprio(0);
        }
    }

    if constexpr (MODE == 0) {
        const int sec = n0 >> 10;
#pragma unroll
        for (int j = 0; j < 2; ++j) {
            int gn = n0 + wn * 32 + j * 16 + lr;
            float bv = bias[gn];
            int nn = gn & 1023, h = nn >> 6, d = nn & 63;
            if (sec == 2) {
#pragma unroll
                for (int i = 0; i < 4; ++i) {
                    int sb = m0 + wm * 64 + i * 16 + lg * 4;
                    size_t bhv = (size_t)((sb >> 11) * NHEAD + h);
                    u16x4 pv;
#pragma unroll
                    for (int r = 0; r < 4; ++r) pv[r] = f2bf(acc[i][j][r] + bv);
                    *reinterpret_cast<u16x4*>(&Vt[(bhv * HDIM + d) * S_LEN + (sb & 2047)]) = pv;
                }
            } else {
#pragma unroll
                for (int i = 0; i < 4; ++i) {
#pragma unroll
                    for (int r = 0; r < 4; ++r) {
                        int m = m0 + wm * 64 + i * 16 + lg * 4 + r;
                        int b_ = m >> 11, s_ = m & 2047;
                        size_t bh = (size_t)(b_ * NHEAD + h);
                        float v = acc[i][j][r] + bv;
                        if (sec == 0)
                            Qb[(bh * S_LEN + s_) * HDIM + d] = f2bf(v * 0.18033688f);  // 1/8*log2(e)
                        else
                            Kb[(bh * S_LEN + s_) * HDIM + d] = f2bf(v);
                    }
                }
            }
        }
    } else {
#pragma unroll
        for (int j = 0; j < 2; ++j) {
            int gn = n0 + wn * 32 + j * 16 + lr;
            float bv = bias[gn];
#pragma unroll
            for (int i = 0; i < 4; ++i) {
#pragma unroll
                for (int r = 0; r < 4; ++r) {
                    int m = m0 + wm * 64 + i * 16 + lg * 4 + r;
                    outf[(size_t)m * DIM + gn] = acc[i][j][r] + bv;
                }
            }
        }
    }
}

// ---------- flash attention: 8 waves (4q x 2k), 64-key tiles, counted-vmcnt ----------
// r17 body; sync replaced with T4 schedule: 3 rotating buffers, per tile
// {compute(buf t%3); issue t+2; s_waitcnt vmcnt(2); raw s_barrier}.
// Prefetched loads stay in flight across barriers (never drained to 0).
__device__ __forceinline__ void repack32(const f32x16& p, bf16x8 (&pa)[2]) {
#pragma unroll
    for (int k2 = 0; k2 < 2; ++k2) {
        const int rb = 8 * k2;
        unsigned aw[2], bw[2];
#pragma unroll
        for (int u = 0; u < 2; ++u) {
            unsigned a, b;
            asm("v_cvt_pk_bf16_f32 %0, %1, %2"
                : "=v"(a) : "v"(p[rb + 2 * u]), "v"(p[rb + 2 * u + 1]));
            asm("v_cvt_pk_bf16_f32 %0, %1, %2"
                : "=v"(b) : "v"(p[rb + 4 + 2 * u]), "v"(p[rb + 4 + 2 * u + 1]));
            asm volatile("v_permlane32_swap_b32 %0, %1" : "+v"(a), "+v"(b));
            aw[u] = a; bw[u] = b;
        }
        union { unsigned w[4]; bf16x8 v; } pu;
        pu.w[0] = aw[0]; pu.w[1] = aw[1]; pu.w[2] = bw[0]; pu.w[3] = bw[1];
        pa[k2] = pu.v;
    }
}

#define NT64 32   // 32 tiles x 64 keys = 2048
__global__ __launch_bounds__(512, 4) void attn_kernel(const unsigned short* __restrict__ Qb,
                                                      const unsigned short* __restrict__ Kb,
                                                      const unsigned short* __restrict__ Vt,
                                                      unsigned short* __restrict__ Ob) {
    __shared__ char smem[3 * 16384 + 512];        // 3 rotating bufs (8KB K + 8KB V) + cls
    const int L = blockIdx.x;                     // 0..511
    const int xcd = L & 7, slot = L >> 3;
    const int bh = xcd + 8 * (slot & 3);          // 4 heads per XCD -> K/V L2-resident
    const int qblk = slot >> 2;                   // 0..15
    const int wid = threadIdx.x >> 6;             // 0..7
    const int lane = threadIdx.x & 63;
    const int l31 = lane & 31, hi = lane >> 5;
    const int qs = wid & 3, kh = wid >> 2;        // kh 0..1
    const int q0 = qblk * 128 + qs * 32;

    const unsigned short* qrow = &Qb[((size_t)bh * S_LEN + q0 + l31) * HDIM];
    bf16x8 qf[4];
#pragma unroll
    for (int kst = 0; kst < 4; ++kst)
        qf[kst] = *reinterpret_cast<const bf16x8*>(&qrow[kst * 16 + hi * 8]);

    bf16x8 onesf;
#pragma unroll
    for (int j = 0; j < 8; ++j) onesf[j] = (short)0x3F80;   // bf16 1.0

    const char* kT = (const char*)&Kb[(size_t)bh * S_LEN * HDIM];  // tile t at +t*8192
    const char* vT = (const char*)&Vt[(size_t)bh * HDIM * S_LEN];  // tile t at +t*128

    // staging: 16 chunks per 64-key tile (ids 0-7 K, 8-15 V); wave stages 2w, 2w+1
    const char* sbase = (wid < 4) ? kT : vT;
    const int tileStride = (wid < 4) ? 8192 : 128;
    int srcOff[2], dstOff[2];
#pragma unroll
    for (int i = 0; i < 2; ++i) {
        int id = 2 * wid + i;
        if (id < 8) {
            int khs = (id >> 2) & 1, kst = id & 3;
            srcOff[i] = (khs * 32 + l31) * 128 + kst * 32 + hi * 16;
        } else {
            int c = id - 8;
            int khs = (c >> 2) & 1, dt = (c >> 1) & 1, k2 = c & 1;
            srcOff[i] = (dt * 32 + l31) * 4096 + khs * 64 + k2 * 32 + hi * 16;
        }
        dstOff[i] = id * 1024;
    }

    f32x16 acc[2] = {};
    f32x16 sacc = {};                              // MFMA row-sums (P . ones)

    // prologue: stage tiles 0 -> buf0, 1 -> buf1; wait for tile 0 only (2 in flight)
#pragma unroll
    for (int i = 0; i < 2; ++i)
        gl_lds16(sbase + srcOff[i], smem + dstOff[i]);
#pragma unroll
    for (int i = 0; i < 2; ++i)
        gl_lds16(sbase + tileStride + srcOff[i], smem + 16384 + dstOff[i]);
    asm volatile("s_waitcnt vmcnt(2)" ::: "memory");
    __builtin_amdgcn_s_barrier();

    const int cofs = kh * 4096;
    for (int t = 0; t < NT64; ++t) {
        const char* bufb = smem + (t % 3) * 16384;
        const char* kbb = bufb + cofs + lane * 16;
        const char* vbb = bufb + 8192 + cofs + lane * 16;

        // QK^T swapped: lane holds q=l31, local key = (r&3)+4*hi+8*(r>>2)
        f32x16 p = {};
        __builtin_amdgcn_s_setprio(1);
#pragma unroll
        for (int kst = 0; kst < 4; ++kst) {
            bf16x8 kb = *reinterpret_cast<const bf16x8*>(kbb + kst * 1024);
            p = mfma32(kb, qf[kst], p);
        }
        __builtin_amdgcn_s_setprio(0);

#pragma unroll
        for (int r = 0; r < 16; ++r) p[r] = fexp2(p[r]);
        bf16x8 pa[2];
        repack32(p, pa);

        __builtin_amdgcn_s_setprio(1);
        sacc = mfma32(pa[0], onesf, sacc);         // row-sums on the MFMA pipe
        sacc = mfma32(pa[1], onesf, sacc);
#pragma unroll
        for (int dt = 0; dt < 2; ++dt)
#pragma unroll
            for (int k2 = 0; k2 < 2; ++k2) {
                bf16x8 vb = *reinterpret_cast<const bf16x8*>(vbb + (dt * 2 + k2) * 1024);
                acc[dt] = mfma32(pa[k2], vb, acc[dt]);
            }
        __builtin_amdgcn_s_setprio(0);

        // T4 counted-vmcnt schedule: issue t+2, wait for t+1 only, one raw barrier.
        if (t + 2 < NT64) {
            char* nb = smem + ((t + 2) % 3) * 16384;
#pragma unroll
            for (int i = 0; i < 2; ++i)
                gl_lds16(sbase + (size_t)(t + 2) * tileStride + srcOff[i], nb + dstOff[i]);
            asm volatile("s_waitcnt vmcnt(2)" ::: "memory");   // t+1 landed; t+2 in flight
            __builtin_amdgcn_s_barrier();
        } else if (t + 1 < NT64) {
            asm volatile("s_waitcnt vmcnt(0)" ::: "memory");   // tail: t+1 landed
            __builtin_amdgcn_s_barrier();
        }
    }

    __syncthreads();   // full drain before smem reuse for the combine

    // cross-wave combine (key halves) via LDS; kh=1 writes, kh=0 reduces+stores
    float* cacc = (float*)smem;                   // [qs][dt][r][lane] f32 = 32KB
    float* cls  = (float*)(smem + 49152);         // [qs][q] 512B
    if (kh == 1) {
#pragma unroll
        for (int dt = 0; dt < 2; ++dt)
#pragma unroll
            for (int r = 0; r < 16; ++r)
                cacc[qs * 2048 + dt * 1024 + r * 64 + lane] = acc[dt][r];
        if (l31 == 0) {
#pragma unroll
            for (int r = 0; r < 16; ++r) {
                int rq = (r & 3) + 8 * (r >> 2) + 4 * hi;
                cls[qs * 32 + rq] = sacc[r];
            }
        }
    }
    __syncthreads();
    if (kh == 0) {
#pragma unroll
        for (int dt = 0; dt < 2; ++dt)
#pragma unroll
            for (int r = 0; r < 16; ++r)
                acc[dt][r] += cacc[qs * 2048 + dt * 1024 + r * 64 + lane];

        const int b_ = bh >> 4, h = bh & 15;
        float inv[16];
#pragma unroll
        for (int r = 0; r < 16; ++r) {
            int rq = (r & 3) + 8 * (r >> 2) + 4 * hi;
            inv[r] = 1.f / (sacc[r] + cls[qs * 32 + rq]);   // broadcast LDS read
        }
#pragma unroll
        for (int dt = 0; dt < 2; ++dt)
#pragma unroll
            for (int r = 0; r < 16; ++r) {
                int rq = (r & 3) + 8 * (r >> 2) + 4 * hi;
                int q = q0 + rq;
                Ob[((size_t)(b_ * S_LEN + q)) * DIM + h * HDIM + dt * 32 + l31] =
                    f2bf_fast(acc[dt][r] * inv[r]);
            }
    }
}

extern "C" void kernel_launch(void* const* d_in, const int* in_sizes, int n_in,
                              void* d_out, int out_size, void* d_ws, size_t ws_size,
                              hipStream_t stream) {
    const float* x      = (const float*)d_in[0];
    const float* qkv_w  = (const float*)d_in[1];
    const float* qkv_b  = (const float*)d_in[2];
    const float* proj_w = (const float*)d_in[3];
    const float* proj_b = (const float*)d_in[4];
    float* out = (float*)d_out;

    unsigned short* Wqkvt = (unsigned short*)d_ws;         // [3072][1024] bf16
    unsigned short* Wpt   = Wqkvt + 3072 * 1024;           // [1024][1024] bf16
    unsigned short* Qb    = Wpt + 1024 * 1024;             // [32][2048][64] bf16 (scale*log2e folded)
    unsigned short* Kb    = Qb + 32 * 2048 * 64;           // [32][2048][64]
    unsigned short* Vt    = Kb + 32 * 2048 * 64;           // [32][64][2048]
    unsigned short* Ob    = Vt + 32 * 2048 * 64;           // [4096][1024] bf16
    unsigned short* Xb    = Ob + 4096 * 1024;              // [4096][1024] bf16

    prep_kernel<<<3072, 256, 0, stream>>>(x, Xb, qkv_w, Wqkvt, proj_w, Wpt);

    gemm_kernel<0><<<dim3(32, 24), 512, 0, stream>>>(Xb, Wqkvt, qkv_b, Qb, Kb, Vt, nullptr);
    attn_kernel<<<512, 512, 0, stream>>>(Qb, Kb, Vt, Ob);
    gemm_kernel<1><<<dim3(32, 8), 512, 0, stream>>>(Ob, Wpt, proj_b, nullptr, nullptr, nullptr, out);
}

// Round 20
// 104.103 us; speedup vs baseline: 1.1147x; 1.0409x over previous
//
#include <hip/hip_runtime.h>
#include <hip/hip_bf16.h>

typedef __attribute__((ext_vector_type(8))) short bf16x8;
typedef __attribute__((ext_vector_type(4))) float f32x4;
typedef __attribute__((ext_vector_type(16))) float f32x16;
typedef __attribute__((ext_vector_type(4))) unsigned short u16x4;
typedef __attribute__((ext_vector_type(8))) unsigned short u16x8v;

#define S_LEN 2048
#define NHEAD 16
#define HDIM 64
#define DIM 1024

__device__ __forceinline__ unsigned short f2bf(float f) {
    union { float f; unsigned u; } x; x.f = f;
    unsigned r = x.u + 0x7FFFu + ((x.u >> 16) & 1u);
    return (unsigned short)(r >> 16);
}
__device__ __forceinline__ unsigned short f2bf_fast(float f) {
    union { float f; unsigned u; } x; x.f = f;
    return (unsigned short)((x.u + 0x8000u) >> 16);
}

__device__ __forceinline__ f32x4 mfma16(bf16x8 a, bf16x8 b, f32x4 c) {
    return __builtin_amdgcn_mfma_f32_16x16x32_bf16(a, b, c, 0, 0, 0);
}
__device__ __forceinline__ f32x16 mfma32(bf16x8 a, bf16x8 b, f32x16 c) {
    return __builtin_amdgcn_mfma_f32_32x32x16_bf16(a, b, c, 0, 0, 0);
}

__device__ __forceinline__ float fexp2(float x) {
#if __has_builtin(__builtin_amdgcn_exp2f)
    return __builtin_amdgcn_exp2f(x);
#else
    return exp2f(x);
#endif
}

__device__ __forceinline__ void gl_lds16(const void* g, void* l) {
    __builtin_amdgcn_global_load_lds(
        (const __attribute__((address_space(1))) unsigned int*)g,
        (__attribute__((address_space(3))) unsigned int*)l, 16, 0, 0);
}

// ---------- fused prep: xconv (blocks 0..2047) + wtrans qkv + wtrans proj ----------
__device__ __forceinline__ void wtrans_body(const float* __restrict__ W,
                                            unsigned short* __restrict__ Wt,
                                            int K, int N, int k0, int n0,
                                            float (*lds)[65], int tid) {
    for (int idx = tid; idx < 1024; idx += 256) {
        int row = idx >> 4, c = (idx & 15) << 2;
        float4 v = *reinterpret_cast<const float4*>(&W[(size_t)(k0 + row) * N + n0 + c]);
        lds[row][c] = v.x; lds[row][c + 1] = v.y; lds[row][c + 2] = v.z; lds[row][c + 3] = v.w;
    }
    __syncthreads();
    for (int idx = tid; idx < 1024; idx += 256) {
        int row = idx >> 4, c = (idx & 15) << 2;
        u16x4 o;
        o[0] = f2bf(lds[c][row]);     o[1] = f2bf(lds[c + 1][row]);
        o[2] = f2bf(lds[c + 2][row]); o[3] = f2bf(lds[c + 3][row]);
        *reinterpret_cast<u16x4*>(&Wt[(size_t)(n0 + row) * K + k0 + c]) = o;
    }
}

__global__ __launch_bounds__(256) void prep_kernel(const float* __restrict__ X,
                                                   unsigned short* __restrict__ Xb,
                                                   const float* __restrict__ Wq,
                                                   unsigned short* __restrict__ Wqt,
                                                   const float* __restrict__ Wp,
                                                   unsigned short* __restrict__ Wpt) {
    __shared__ float lds[64][65];
    const int b = blockIdx.x, tid = threadIdx.x;
    if (b < 2048) {
        size_t i = ((size_t)b * 256 + tid) * 8;
        float4 a = *reinterpret_cast<const float4*>(&X[i]);
        float4 c = *reinterpret_cast<const float4*>(&X[i + 4]);
        u16x8v o;
        o[0] = f2bf(a.x); o[1] = f2bf(a.y); o[2] = f2bf(a.z); o[3] = f2bf(a.w);
        o[4] = f2bf(c.x); o[5] = f2bf(c.y); o[6] = f2bf(c.z); o[7] = f2bf(c.w);
        *reinterpret_cast<u16x8v*>(&Xb[i]) = o;
    } else if (b < 2816) {
        int idx = b - 2048;
        wtrans_body(Wq, Wqt, 1024, 3072, (idx & 15) * 64, (idx >> 4) * 64, lds, tid);
    } else {
        int idx = b - 2816;
        wtrans_body(Wp, Wpt, 1024, 1024, (idx & 15) * 64, (idx >> 4) * 64, lds, tid);
    }
}

// ---------- GEMM: 128x128 tile, BK=64, 8 waves x (64x32), T4 counted-vmcnt dbuf ----------
// Per K-step: compute buf[kt&1]; barrier (readers done); issue kt+2 into same buf;
// s_waitcnt vmcnt(4) (kt+1 landed, kt+2 in flight); barrier. No vmcnt(0) in loop.
template <int MODE>
__global__ __launch_bounds__(512) void gemm_kernel(
    const unsigned short* __restrict__ Ab, const unsigned short* __restrict__ Bt,
    const float* __restrict__ bias,
    unsigned short* __restrict__ Qb, unsigned short* __restrict__ Kb,
    unsigned short* __restrict__ Vt, float* __restrict__ outf) {
    __shared__ unsigned short Alds[2][128 * 64];   // 2 x 16KB, swizzled
    __shared__ unsigned short Blds[2][128 * 64];
    const int tid = threadIdx.x;
    const int m0 = blockIdx.x * 128, n0 = blockIdx.y * 128;
    const int wid = tid >> 6, lane = tid & 63;
    const int wm = wid >> 2, wn = wid & 3;      // 2 x 4 wave grid
    const int lr = lane & 15, lg = lane >> 4;

    const char* Abase = (const char*)(Ab + (size_t)m0 * 1024);
    const char* Bbase = (const char*)(Bt + (size_t)n0 * 1024);

    int srcOff[2], dstOff[2];
#pragma unroll
    for (int i = 0; i < 2; ++i) {
        int off = i * 8192 + tid * 16;
        int row = off >> 7, col = off & 127;
        srcOff[i] = row * 2048 + (col ^ ((row & 7) << 4));
        dstOff[i] = off;
    }
    const int swz = (lr & 7) << 4;

    f32x4 acc[4][2] = {};

    // prologue: stage K-tiles 0 and 1; wait for tile 0 only (tile 1 in flight)
#pragma unroll
    for (int i = 0; i < 2; ++i) {
        gl_lds16(Abase + srcOff[i], (char*)Alds[0] + dstOff[i]);
        gl_lds16(Bbase + srcOff[i], (char*)Blds[0] + dstOff[i]);
    }
#pragma unroll
    for (int i = 0; i < 2; ++i) {
        gl_lds16(Abase + srcOff[i] + 128, (char*)Alds[1] + dstOff[i]);
        gl_lds16(Bbase + srcOff[i] + 128, (char*)Blds[1] + dstOff[i]);
    }
    asm volatile("s_waitcnt vmcnt(4)" ::: "memory");
    __builtin_amdgcn_s_barrier();

    for (int kt = 0; kt < 16; ++kt) {
        const int cb = kt & 1;
#pragma unroll
        for (int ks = 0; ks < 2; ++ks) {
            bf16x8 af[4], bfr[2];
#pragma unroll
            for (int i = 0; i < 4; ++i)
                af[i] = *reinterpret_cast<const bf16x8*>(
                    (const char*)Alds[cb] + (wm * 64 + i * 16 + lr) * 128 + ((ks * 64 + lg * 16) ^ swz));
#pragma unroll
            for (int j = 0; j < 2; ++j)
                bfr[j] = *reinterpret_cast<const bf16x8*>(
                    (const char*)Blds[cb] + (wn * 32 + j * 16 + lr) * 128 + ((ks * 64 + lg * 16) ^ swz));
            __builtin_amdgcn_s_setprio(1);
#pragma unroll
            for (int i = 0; i < 4; ++i)
#pragma unroll
                for (int j = 0; j < 2; ++j)
                    acc[i][j] = mfma16(af[i], bfr[j], acc[i][j]);
            __builtin_amdgcn_s_setprio(0);
        }
        if (kt + 1 < 16) {
            __builtin_amdgcn_s_barrier();           // all waves done reading buf[cb]
            if (kt + 2 < 16) {
#pragma unroll
                for (int i = 0; i < 2; ++i) {
                    gl_lds16(Abase + srcOff[i] + (kt + 2) * 128, (char*)Alds[cb] + dstOff[i]);
                    gl_lds16(Bbase + srcOff[i] + (kt + 2) * 128, (char*)Blds[cb] + dstOff[i]);
                }
                asm volatile("s_waitcnt vmcnt(4)" ::: "memory");  // kt+1 landed
            } else {
                asm volatile("s_waitcnt vmcnt(0)" ::: "memory");  // tail: kt+1 landed
            }
            __builtin_amdgcn_s_barrier();
        }
    }

    if constexpr (MODE == 0) {
        const int sec = n0 >> 10;
#pragma unroll
        for (int j = 0; j < 2; ++j) {
            int gn = n0 + wn * 32 + j * 16 + lr;
            float bv = bias[gn];
            int nn = gn & 1023, h = nn >> 6, d = nn & 63;
            if (sec == 2) {
#pragma unroll
                for (int i = 0; i < 4; ++i) {
                    int sb = m0 + wm * 64 + i * 16 + lg * 4;
                    size_t bhv = (size_t)((sb >> 11) * NHEAD + h);
                    u16x4 pv;
#pragma unroll
                    for (int r = 0; r < 4; ++r) pv[r] = f2bf(acc[i][j][r] + bv);
                    *reinterpret_cast<u16x4*>(&Vt[(bhv * HDIM + d) * S_LEN + (sb & 2047)]) = pv;
                }
            } else {
#pragma unroll
                for (int i = 0; i < 4; ++i) {
#pragma unroll
                    for (int r = 0; r < 4; ++r) {
                        int m = m0 + wm * 64 + i * 16 + lg * 4 + r;
                        int b_ = m >> 11, s_ = m & 2047;
                        size_t bh = (size_t)(b_ * NHEAD + h);
                        float v = acc[i][j][r] + bv;
                        if (sec == 0)
                            Qb[(bh * S_LEN + s_) * HDIM + d] = f2bf(v * 0.18033688f);  // 1/8*log2(e)
                        else
                            Kb[(bh * S_LEN + s_) * HDIM + d] = f2bf(v);
                    }
                }
            }
        }
    } else {
#pragma unroll
        for (int j = 0; j < 2; ++j) {
            int gn = n0 + wn * 32 + j * 16 + lr;
            float bv = bias[gn];
#pragma unroll
            for (int i = 0; i < 4; ++i) {
#pragma unroll
                for (int r = 0; r < 4; ++r) {
                    int m = m0 + wm * 64 + i * 16 + lg * 4 + r;
                    outf[(size_t)m * DIM + gn] = acc[i][j][r] + bv;
                }
            }
        }
    }
}

// ---------- flash attention: 8 waves (4q x 2k), 64-key tiles, counted-vmcnt (r19) ----------
__device__ __forceinline__ void repack32(const f32x16& p, bf16x8 (&pa)[2]) {
#pragma unroll
    for (int k2 = 0; k2 < 2; ++k2) {
        const int rb = 8 * k2;
        unsigned aw[2], bw[2];
#pragma unroll
        for (int u = 0; u < 2; ++u) {
            unsigned a, b;
            asm("v_cvt_pk_bf16_f32 %0, %1, %2"
                : "=v"(a) : "v"(p[rb + 2 * u]), "v"(p[rb + 2 * u + 1]));
            asm("v_cvt_pk_bf16_f32 %0, %1, %2"
                : "=v"(b) : "v"(p[rb + 4 + 2 * u]), "v"(p[rb + 4 + 2 * u + 1]));
            asm volatile("v_permlane32_swap_b32 %0, %1" : "+v"(a), "+v"(b));
            aw[u] = a; bw[u] = b;
        }
        union { unsigned w[4]; bf16x8 v; } pu;
        pu.w[0] = aw[0]; pu.w[1] = aw[1]; pu.w[2] = bw[0]; pu.w[3] = bw[1];
        pa[k2] = pu.v;
    }
}

#define NT64 32   // 32 tiles x 64 keys = 2048
__global__ __launch_bounds__(512, 4) void attn_kernel(const unsigned short* __restrict__ Qb,
                                                      const unsigned short* __restrict__ Kb,
                                                      const unsigned short* __restrict__ Vt,
                                                      unsigned short* __restrict__ Ob) {
    __shared__ char smem[3 * 16384 + 512];        // 3 rotating bufs (8KB K + 8KB V) + cls
    const int L = blockIdx.x;                     // 0..511
    const int xcd = L & 7, slot = L >> 3;
    const int bh = xcd + 8 * (slot & 3);          // 4 heads per XCD -> K/V L2-resident
    const int qblk = slot >> 2;                   // 0..15
    const int wid = threadIdx.x >> 6;             // 0..7
    const int lane = threadIdx.x & 63;
    const int l31 = lane & 31, hi = lane >> 5;
    const int qs = wid & 3, kh = wid >> 2;        // kh 0..1
    const int q0 = qblk * 128 + qs * 32;

    const unsigned short* qrow = &Qb[((size_t)bh * S_LEN + q0 + l31) * HDIM];
    bf16x8 qf[4];
#pragma unroll
    for (int kst = 0; kst < 4; ++kst)
        qf[kst] = *reinterpret_cast<const bf16x8*>(&qrow[kst * 16 + hi * 8]);

    bf16x8 onesf;
#pragma unroll
    for (int j = 0; j < 8; ++j) onesf[j] = (short)0x3F80;   // bf16 1.0

    const char* kT = (const char*)&Kb[(size_t)bh * S_LEN * HDIM];  // tile t at +t*8192
    const char* vT = (const char*)&Vt[(size_t)bh * HDIM * S_LEN];  // tile t at +t*128

    const char* sbase = (wid < 4) ? kT : vT;
    const int tileStride = (wid < 4) ? 8192 : 128;
    int srcOff[2], dstOff[2];
#pragma unroll
    for (int i = 0; i < 2; ++i) {
        int id = 2 * wid + i;
        if (id < 8) {
            int khs = (id >> 2) & 1, kst = id & 3;
            srcOff[i] = (khs * 32 + l31) * 128 + kst * 32 + hi * 16;
        } else {
            int c = id - 8;
            int khs = (c >> 2) & 1, dt = (c >> 1) & 1, k2 = c & 1;
            srcOff[i] = (dt * 32 + l31) * 4096 + khs * 64 + k2 * 32 + hi * 16;
        }
        dstOff[i] = id * 1024;
    }

    f32x16 acc[2] = {};
    f32x16 sacc = {};                              // MFMA row-sums (P . ones)

    // prologue: stage tiles 0 -> buf0, 1 -> buf1; wait for tile 0 only
#pragma unroll
    for (int i = 0; i < 2; ++i)
        gl_lds16(sbase + srcOff[i], smem + dstOff[i]);
#pragma unroll
    for (int i = 0; i < 2; ++i)
        gl_lds16(sbase + tileStride + srcOff[i], smem + 16384 + dstOff[i]);
    asm volatile("s_waitcnt vmcnt(2)" ::: "memory");
    __builtin_amdgcn_s_barrier();

    const int cofs = kh * 4096;
    for (int t = 0; t < NT64; ++t) {
        const char* bufb = smem + (t % 3) * 16384;
        const char* kbb = bufb + cofs + lane * 16;
        const char* vbb = bufb + 8192 + cofs + lane * 16;

        // QK^T swapped: lane holds q=l31, local key = (r&3)+4*hi+8*(r>>2)
        f32x16 p = {};
        __builtin_amdgcn_s_setprio(1);
#pragma unroll
        for (int kst = 0; kst < 4; ++kst) {
            bf16x8 kb = *reinterpret_cast<const bf16x8*>(kbb + kst * 1024);
            p = mfma32(kb, qf[kst], p);
        }
        __builtin_amdgcn_s_setprio(0);

#pragma unroll
        for (int r = 0; r < 16; ++r) p[r] = fexp2(p[r]);
        bf16x8 pa[2];
        repack32(p, pa);

        __builtin_amdgcn_s_setprio(1);
        sacc = mfma32(pa[0], onesf, sacc);         // row-sums on the MFMA pipe
        sacc = mfma32(pa[1], onesf, sacc);
#pragma unroll
        for (int dt = 0; dt < 2; ++dt)
#pragma unroll
            for (int k2 = 0; k2 < 2; ++k2) {
                bf16x8 vb = *reinterpret_cast<const bf16x8*>(vbb + (dt * 2 + k2) * 1024);
                acc[dt] = mfma32(pa[k2], vb, acc[dt]);
            }
        __builtin_amdgcn_s_setprio(0);

        // T4 counted-vmcnt: issue t+2, wait for t+1 only, one raw barrier.
        if (t + 2 < NT64) {
            char* nb = smem + ((t + 2) % 3) * 16384;
#pragma unroll
            for (int i = 0; i < 2; ++i)
                gl_lds16(sbase + (size_t)(t + 2) * tileStride + srcOff[i], nb + dstOff[i]);
            asm volatile("s_waitcnt vmcnt(2)" ::: "memory");   // t+1 landed; t+2 in flight
            __builtin_amdgcn_s_barrier();
        } else if (t + 1 < NT64) {
            asm volatile("s_waitcnt vmcnt(0)" ::: "memory");   // tail: t+1 landed
            __builtin_amdgcn_s_barrier();
        }
    }

    __syncthreads();   // full drain before smem reuse for the combine

    // cross-wave combine (key halves) via LDS; kh=1 writes, kh=0 reduces+stores
    float* cacc = (float*)smem;                   // [qs][dt][r][lane] f32 = 32KB
    float* cls  = (float*)(smem + 49152);         // [qs][q] 512B
    if (kh == 1) {
#pragma unroll
        for (int dt = 0; dt < 2; ++dt)
#pragma unroll
            for (int r = 0; r < 16; ++r)
                cacc[qs * 2048 + dt * 1024 + r * 64 + lane] = acc[dt][r];
        if (l31 == 0) {
#pragma unroll
            for (int r = 0; r < 16; ++r) {
                int rq = (r & 3) + 8 * (r >> 2) + 4 * hi;
                cls[qs * 32 + rq] = sacc[r];
            }
        }
    }
    __syncthreads();
    if (kh == 0) {
#pragma unroll
        for (int dt = 0; dt < 2; ++dt)
#pragma unroll
            for (int r = 0; r < 16; ++r)
                acc[dt][r] += cacc[qs * 2048 + dt * 1024 + r * 64 + lane];

        const int b_ = bh >> 4, h = bh & 15;
        float inv[16];
#pragma unroll
        for (int r = 0; r < 16; ++r) {
            int rq = (r & 3) + 8 * (r >> 2) + 4 * hi;
            inv[r] = 1.f / (sacc[r] + cls[qs * 32 + rq]);   // broadcast LDS read
        }
#pragma unroll
        for (int dt = 0; dt < 2; ++dt)
#pragma unroll
            for (int r = 0; r < 16; ++r) {
                int rq = (r & 3) + 8 * (r >> 2) + 4 * hi;
                int q = q0 + rq;
                Ob[((size_t)(b_ * S_LEN + q)) * DIM + h * HDIM + dt * 32 + l31] =
                    f2bf_fast(acc[dt][r] * inv[r]);
            }
    }
}

extern "C" void kernel_launch(void* const* d_in, const int* in_sizes, int n_in,
                              void* d_out, int out_size, void* d_ws, size_t ws_size,
                              hipStream_t stream) {
    const float* x      = (const float*)d_in[0];
    const float* qkv_w  = (const float*)d_in[1];
    const float* qkv_b  = (const float*)d_in[2];
    const float* proj_w = (const float*)d_in[3];
    const float* proj_b = (const float*)d_in[4];
    float* out = (float*)d_out;

    unsigned short* Wqkvt = (unsigned short*)d_ws;         // [3072][1024] bf16
    unsigned short* Wpt   = Wqkvt + 3072 * 1024;           // [1024][1024] bf16
    unsigned short* Qb    = Wpt + 1024 * 1024;             // [32][2048][64] bf16 (scale*log2e folded)
    unsigned short* Kb    = Qb + 32 * 2048 * 64;           // [32][2048][64]
    unsigned short* Vt    = Kb + 32 * 2048 * 64;           // [32][64][2048]
    unsigned short* Ob    = Vt + 32 * 2048 * 64;           // [4096][1024] bf16
    unsigned short* Xb    = Ob + 4096 * 1024;              // [4096][1024] bf16

    prep_kernel<<<3072, 256, 0, stream>>>(x, Xb, qkv_w, Wqkvt, proj_w, Wpt);

    gemm_kernel<0><<<dim3(32, 24), 512, 0, stream>>>(Xb, Wqkvt, qkv_b, Qb, Kb, Vt, nullptr);
    attn_kernel<<<512, 512, 0, stream>>>(Qb, Kb, Vt, Ob);
    gemm_kernel<1><<<dim3(32, 8), 512, 0, stream>>>(Ob, Wpt, proj_b, nullptr, nullptr, nullptr, out);
}